// Round 8
// baseline (115.958 us; speedup 1.0000x reference)
//
#include <hip/hip_runtime.h>

// MetaUpSampler via bf16 MFMA — round 15 (fused: R14 pipeline + direct NCHW).
// R14 post-mortem: pipeline thesis CONFIRMED (118.6->113.0; meta 22->16.4us).
// Ledger: F~84 fixed (fill 43 + memsets/gaps), prep ~13, meta ~16.4.
// R15: delete the xt round trip (prep reads 37.7MB + writes 18.9MB; meta
//   re-reads it). R11's fused attempt failed in the PHASE-LOCKED regime;
//   under R14's persistent 3-tile pipeline the NCHW-f32 window load
//   (84.5KB/tile, 264B-coalesced dword loads) hides under MFMA+stores.
//   Prefetch goes to RAW float regs from clamped addresses (ok-mask applied
//   only at ds_write) so no vmcnt wait lands before the MFMA phase.
//   LDS image is bit-identical to validated R12/R14 (same f2bf + cb^(j&7)
//   swizzle) -> MFMA loop/epilogue untouched, output bit-identical.
// Predict: lw ~3us standalone, fused meta ~14-17us, dur 113 -> ~100-106.
// Workspace: lwb @ 0 (55KB) only; xt eliminated.

#define HH   192
#define WWD  192
#define SS   4
#define OC   3
#define PO   48
#define HID  256
#define W2LD 1728
#define BUFS 21120            // shorts per xlds buffer: 5*66*64
#define CST  (HH * WWD)       // channel stride in floats

typedef short  bf16x8 __attribute__((ext_vector_type(8)));
typedef float  f32x4  __attribute__((ext_vector_type(4)));

static __device__ __forceinline__ short f2bf(float f) {
    unsigned u = __float_as_uint(f);
    unsigned r = (u + 0x7fffu + ((u >> 16) & 1u)) >> 16;   // RNE
    return (short)r;
}

static __device__ __forceinline__ void pin(bf16x8& v) {
    asm volatile("" : "+v"(v));    // force VGPR residency; block load sinking
}

// ---------------- Stage A: MLP -> dynamic weights, bf16, [tap][po][c] -------
__global__ __launch_bounds__(256) void lw_kernel(
        const float* __restrict__ W1, const float* __restrict__ b1,
        const float* __restrict__ W2, const float* __restrict__ b2,
        short* __restrict__ lwb) {
    __shared__ float hlds[HID];
    const int b = blockIdx.x;
    const int t = threadIdx.x;
    const int p = b / 7;
    {
        const float pi = (float)(p >> 2) * 0.25f;
        const float pj = (float)(p & 3) * 0.25f;
        const float v = 0.25f * W1[t] + pi * W1[HID + t] + pj * W1[2 * HID + t]
                      + b1[t];
        hlds[t] = v > 0.f ? v : 0.f;
    }
    __syncthreads();
    const int col = (b % 7) * 256 + t;   // 0..1791 (guard at 1728)
    if (col < W2LD) {
        float a = 0.f;
#pragma unroll 32
        for (int hh = 0; hh < HID; ++hh)
            a += hlds[hh] * W2[hh * W2LD + col];   // coalesced 4B + LDS bcast
        const int o = col % 3, kc = col / 3;
        const int tap = kc % 9, c = kc / 9;
        lwb[(tap * PO + p * 3 + o) * 64 + c] = f2bf(a + b2[col]);
    }
}

// Item decode: item = (r*8 + cb)*66 + j  (j-minor -> 264B-coalesced loads).
// Loads are UNCONDITIONAL from clamped addresses (always in-bounds: channel
// index <= 255, gr/gc clamped to 0). ok-mask applied at write time only, so
// no vmcnt-dependent select is scheduled at the load site.
static __device__ __forceinline__ void stage_load(
        const float* __restrict__ x, int n, int h0, int w0, int tid,
        float fv[7][8]) {
#pragma unroll
    for (int k = 0; k < 7; ++k) {
        const int item = k * 384 + tid;
        const int r  = item / 528;
        const int rm = item - r * 528;
        const int cb = rm / 66;
        const int j  = rm - cb * 66;
        const int gr = h0 - 1 + r, gc = w0 - 1 + j;
        const int grc = (unsigned)gr < (unsigned)HH ? gr : 0;
        const int gcc = (unsigned)gc < (unsigned)WWD ? gc : 0;
        const float* __restrict__ p = x +
            ((size_t)(n * 64 + cb * 8) * HH + grc) * WWD + gcc;
#pragma unroll
        for (int cc = 0; cc < 8; ++cc)
            fv[k][cc] = p[(size_t)cc * CST];
    }
}

static __device__ __forceinline__ void stage_write(
        short* __restrict__ buf, int h0, int w0, int tid,
        const float fv[7][8]) {
#pragma unroll
    for (int k = 0; k < 7; ++k) {
        const int item = k * 384 + tid;
        if (item < 2640) {
            const int r  = item / 528;
            const int rm = item - r * 528;
            const int cb = rm / 66;
            const int j  = rm - cb * 66;
            const int gr = h0 - 1 + r, gc = w0 - 1 + j;
            const bool ok = ((unsigned)gr < (unsigned)HH) &&
                            ((unsigned)gc < (unsigned)WWD);
            bf16x8 pk;
#pragma unroll
            for (int cc = 0; cc < 8; ++cc)
                pk[cc] = f2bf(ok ? fv[k][cc] : 0.f);
            *(bf16x8*)&buf[(r * 66 + j) * 64 + ((cb ^ (j & 7)) << 3)] = pk;
        }
    }
}

// ---------------- Stage B: persistent pipelined fused conv -----------------
__global__ __launch_bounds__(384, 1) void meta_up_mfma(
        const float* __restrict__ x, const short* __restrict__ lwb,
        float* __restrict__ out) {
    // 2 xlds buffers + separate obuf: 84,480 + 37,440 = 121,920 B.
    __shared__ __align__(16) short smem[2 * BUFS + 18720];
    float* obuf = (float*)&smem[2 * BUFS];

    const int xcd = blockIdx.x & 7;       // HW: block b -> XCD b%8
    const int ii  = blockIdx.x >> 3;      // 0..31 within XCD
    const int tid = threadIdx.x;
    const int lane = tid & 63;
    const int wv   = (tid >> 6) % 3;      // po-tile
    const int wgq  = (tid >> 6) / 3;      // m-tile half
    const int quad = lane >> 4, l15 = lane & 15;

    // B fragments: tile-invariant -> load all 18 once, pin to VGPRs.
    bf16x8 Bf[18];
#pragma unroll
    for (int tap = 0; tap < 9; ++tap)
#pragma unroll
        for (int kc2 = 0; kc2 < 2; ++kc2)
            Bf[tap * 2 + kc2] = *(const bf16x8*)
                &lwb[(tap * PO + wv * 16 + l15) * 64 + kc2 * 32 + quad * 8];
#pragma unroll
    for (int i = 0; i < 18; ++i) pin(Bf[i]);

    // Tile decode: tau = 96*xcd + 3*ii + t -> consecutive hg per block
    // (tile t+1's overlap rows are L2/own-CU warm).
    int n_c, h0_c, w0_c;
    {
        const int tau = 96 * xcd + 3 * ii;
        n_c = tau / 192;
        const int rem = tau % 192;
        w0_c = (rem / 64) * 64;
        h0_c = (rem % 64) * 3;
    }

    float fv[7][8];
    // ---- prologue: stage tile 0 into buf0 ---------------------------------
    stage_load(x, n_c, h0_c, w0_c, tid, fv);
    stage_write(smem, h0_c, w0_c, tid, fv);
    __syncthreads();

    for (int t = 0; t < 3; ++t) {
        int n_n = n_c, h0_n = h0_c, w0_n = w0_c;
        if (t < 2) {
            // decode tile t+1 and ISSUE its loads (hide under MFMA + stores)
            const int tau = 96 * xcd + 3 * ii + t + 1;
            n_n = tau / 192;
            const int rem = tau % 192;
            w0_n = (rem / 64) * 64;
            h0_n = (rem % 64) * 3;
            stage_load(x, n_n, h0_n, w0_n, tid, fv);
        }

        // ---- MFMA phase on buffer t&1 (validated R12 loop) ----------------
        const short* __restrict__ xb = &smem[(t & 1) * BUFS];
        f32x4 acc[3][2];
#pragma unroll
        for (int ih = 0; ih < 3; ++ih)
#pragma unroll
            for (int mtl = 0; mtl < 2; ++mtl)
                acc[ih][mtl] = (f32x4){0.f, 0.f, 0.f, 0.f};

#pragma unroll
        for (int b = 0; b < 6; ++b) {
            const int dj = b >> 1, kc2 = b & 1;
#pragma unroll
            for (int mtl = 0; mtl < 2; ++mtl) {
                const int mt  = wgq * 2 + mtl;
                const int col = mt * 16 + l15 + dj;      // 0..65
                const int blk = (kc2 * 4 + quad) ^ (col & 7);
#pragma unroll
                for (int r = 0; r < 5; ++r) {
                    bf16x8 a = *(const bf16x8*)&xb[(r * 66 + col) * 64 + (blk << 3)];
#pragma unroll
                    for (int di = 0; di < 3; ++di) {
                        const int ih = r - di;
                        if (ih >= 0 && ih < 3)
                            acc[ih][mtl] = __builtin_amdgcn_mfma_f32_16x16x32_bf16(
                                a, Bf[(di * 3 + dj) * 2 + kc2], acc[ih][mtl], 0, 0, 0);
                    }
                }
            }
        }

        // ---- epilogue: D -> obuf (separate LDS region) --------------------
        {
            const int po = wv * 16 + l15;
            const int o  = po % 3;
            const int p  = po / 3;
            const int si = p >> 2, sj = p & 3;
            const int osi = o * 4 + si;
#pragma unroll
            for (int ih = 0; ih < 3; ++ih)
#pragma unroll
                for (int mtl = 0; mtl < 2; ++mtl) {
                    const int mt = wgq * 2 + mtl;
#pragma unroll
                    for (int r4 = 0; r4 < 4; ++r4) {
                        const int wl = mt * 16 + quad * 4 + r4;
                        obuf[(ih * 12 + osi) * 260 + wl * 4 + sj] = acc[ih][mtl][r4];
                    }
                }
        }
        __syncthreads();                   // obuf visible; xlds(t) reads done

        // ---- coalesced out stores (overlap next tile's loads in flight) ---
#pragma unroll
        for (int ih = 0; ih < 3; ++ih)
#pragma unroll
            for (int h2 = 0; h2 < 2; ++h2) {
                const int idx = h2 * 384 + tid;      // 0..767
                const int osi = idx >> 6;            // 0..11
                const int c4  = idx & 63;
                const int o = osi >> 2, si = osi & 3;
                const int hh = h0_c + ih;
                const size_t base =
                    ((size_t)(n_c * OC + o) * (SS * HH) + (size_t)(SS * hh + si))
                        * (SS * WWD) + (size_t)(4 * w0_c) + c4 * 4;
                *(float4*)&out[base] =
                    *(const float4*)&obuf[(ih * 12 + osi) * 260 + c4 * 4];
            }

        if (t < 2) {
            // first use of fv -> single vmcnt wait lands HERE, after MFMA
            stage_write(&smem[((t + 1) & 1) * BUFS], h0_n, w0_n, tid, fv);
            __syncthreads();               // buf(t+1) visible before MFMA(t+1)
            n_c = n_n; h0_c = h0_n; w0_c = w0_n;
        }
    }
}

extern "C" void kernel_launch(void* const* d_in, const int* in_sizes, int n_in,
                              void* d_out, int out_size, void* d_ws, size_t ws_size,
                              hipStream_t stream) {
    const float* x  = (const float*)d_in[0];
    const float* W1 = (const float*)d_in[1];
    const float* b1 = (const float*)d_in[2];
    const float* W2 = (const float*)d_in[3];
    const float* b2 = (const float*)d_in[4];
    float* out = (float*)d_out;
    short* lwb = (short*)d_ws;                  // 27,648 bf16 = 55 KB

    lw_kernel<<<112, 256, 0, stream>>>(W1, b1, W2, b2, lwb);
    meta_up_mfma<<<256, 384, 0, stream>>>(x, lwb, out);
}

// Round 9
// 113.416 us; speedup vs baseline: 1.0224x; 1.0224x over previous
//
#include <hip/hip_runtime.h>

// MetaUpSampler via bf16 MFMA — round 16 (= R14 + 12-wave meta).
// R15 post-mortem: fused direct-NCHW meta = 43.5us (visible above fill!),
//   21120 scalar-dword VMEM/tile at 6 waves/CU (occ 14.6%) -> VMEM-issue +
//   latency bound. Direct NCHW refuted in BOTH regimes (R11, R15). xt split
//   (R14, 113.0us: prep ~13, meta ~16.4) is the right structure.
// meta_R14 model: per tile load 42.2KB ~3.4us (per-CU HBM share) vs
//   MFMA+store ~2.3us; + unhidden 3.4us prologue => ~16us. Binding term:
//   achieved load BW at only 6 waves/CU. In the PIPELINED regime (unlike
//   R12's phase-locked null) more waves = more outstanding loads = more BW.
// R16: meta = 768 threads / 12 waves; wave w -> wv=w%3 (po-tile), mt=w/3
//   (one m-tile). Per wave: 30 ds_reads, 54 MFMAs, acc[3]. LDS unchanged
//   121.9KB -> still 1 block/CU (VGPR can't hurt occupancy). Staging spread
//   over 768 threads (4 items/thread); stores exactly 1 float4/thread/ih.
//   LDS image/swizzle/B-frags/prep byte-identical to validated R14.
// Predict: meta ~10-12us (occ ~29%), dur 113.0 -> ~106-109, top-5 all-fill.
// Workspace: lwb @ 0 (55KB), xt @ +64KB (18.9MB).

#define HH   192
#define WWD  192
#define SS   4
#define OC   3
#define PO   48
#define HID  256
#define W2LD 1728
#define BUFS 21120   // shorts per xlds buffer: 5*66*64

typedef short  bf16x8 __attribute__((ext_vector_type(8)));
typedef float  f32x4  __attribute__((ext_vector_type(4)));

static __device__ __forceinline__ short f2bf(float f) {
    unsigned u = __float_as_uint(f);
    unsigned r = (u + 0x7fffu + ((u >> 16) & 1u)) >> 16;   // RNE
    return (short)r;
}

static __device__ __forceinline__ void pin(bf16x8& v) {
    asm volatile("" : "+v"(v));    // force VGPR residency; block load sinking
}

// ---------------- Stage A (fused): MLP -> weights  +  x -> NHWC bf16 -------
__global__ __launch_bounds__(256) void prep_kernel(
        const float* __restrict__ x,
        const float* __restrict__ W1, const float* __restrict__ b1,
        const float* __restrict__ W2, const float* __restrict__ b2,
        short* __restrict__ lwb, short* __restrict__ xt) {
    const int b = blockIdx.x;
    const int t = threadIdx.x;
    if (b < 112) {
        __shared__ float hlds[HID];
        const int p = b / 7;
        {
            const float pi = (float)(p >> 2) * 0.25f;
            const float pj = (float)(p & 3) * 0.25f;
            const float v = 0.25f * W1[t] + pi * W1[HID + t] + pj * W1[2 * HID + t]
                          + b1[t];
            hlds[t] = v > 0.f ? v : 0.f;
        }
        __syncthreads();
        const int col = (b % 7) * 256 + t;   // 0..1791 (guard at 1728)
        if (col < W2LD) {
            float a = 0.f;
#pragma unroll 32
            for (int hh = 0; hh < HID; ++hh)
                a += hlds[hh] * W2[hh * W2LD + col];   // coalesced 4B + LDS bcast
            const int o = col % 3, kc = col / 3;
            const int tap = kc % 9, c = kc / 9;
            lwb[(tap * PO + p * 3 + o) * 64 + c] = f2bf(a + b2[col]);
        }
    } else {
        __shared__ short tl[64][72];         // [w][c], +8 pad vs bank stride
        const int bb = b - 112;
        const int wt = bb % 3;
        const int h  = (bb / 3) % HH;
        const int n  = bb / (3 * HH);
        const int w0 = wt * 64;
#pragma unroll
        for (int i = 0; i < 4; ++i) {
            const int idx = i * 256 + t;     // 0..1023
            const int c   = idx >> 4;        // channel 0..63
            const int j4  = idx & 15;        // float4 within 64 w
            const float4 v = *(const float4*)
                &x[(((size_t)(n * 64 + c)) * HH + h) * WWD + w0 + j4 * 4];
            tl[j4 * 4 + 0][c] = f2bf(v.x);
            tl[j4 * 4 + 1][c] = f2bf(v.y);
            tl[j4 * 4 + 2][c] = f2bf(v.z);
            tl[j4 * 4 + 3][c] = f2bf(v.w);
        }
        __syncthreads();
        const int w  = t >> 2;
        const int c0 = (t & 3) * 16;
        short* dst = &xt[(((size_t)n * HH + h) * WWD + w0 + w) * 64 + c0];
        *(bf16x8*)&dst[0] = *(const bf16x8*)&tl[w][c0];
        *(bf16x8*)&dst[8] = *(const bf16x8*)&tl[w][c0 + 8];
    }
}

// ---------------- Stage B: persistent pipelined MFMA conv, 12 waves --------
__global__ __launch_bounds__(768, 1) void meta_up_mfma(
        const short* __restrict__ xt, const short* __restrict__ lwb,
        float* __restrict__ out) {
    // 2 xlds buffers + separate obuf: 84,480 + 37,440 = 121,920 B.
    __shared__ __align__(16) short smem[2 * BUFS + 18720];
    float* obuf = (float*)&smem[2 * BUFS];

    const int xcd = blockIdx.x & 7;       // HW: block b -> XCD b%8
    const int ii  = blockIdx.x >> 3;      // 0..31 within XCD
    const int tid = threadIdx.x;
    const int lane = tid & 63;
    const int wvw  = tid >> 6;            // wave 0..11
    const int wv   = wvw % 3;             // po-tile
    const int mt   = wvw / 3;             // m-tile (one per wave)
    const int quad = lane >> 4, l15 = lane & 15;

    // B fragments: tile-invariant -> load all 18 once, pin to VGPRs.
    bf16x8 Bf[18];
#pragma unroll
    for (int tap = 0; tap < 9; ++tap)
#pragma unroll
        for (int kc2 = 0; kc2 < 2; ++kc2)
            Bf[tap * 2 + kc2] = *(const bf16x8*)
                &lwb[(tap * PO + wv * 16 + l15) * 64 + kc2 * 32 + quad * 8];
#pragma unroll
    for (int i = 0; i < 18; ++i) pin(Bf[i]);

    // Tile decode: tau = 96*xcd + 3*ii + t (consecutive hg -> L2-warm overlap)
    int n_c, h0_c, w0_c;
    {
        const int tau = 96 * xcd + 3 * ii;
        n_c = tau / 192;
        const int rem = tau % 192;
        w0_c = (rem / 64) * 64;
        h0_c = (rem % 64) * 3;
    }

    const bf16x8 z = {0, 0, 0, 0, 0, 0, 0, 0};
    bf16x8 sv[4];                          // 2640 items / 768 threads -> k<4

    // ---- prologue: stage tile 0 into buf0 ---------------------------------
#pragma unroll
    for (int k = 0; k < 4; ++k) {
        const int item = k * 768 + tid;
        const int r  = item / 528;
        const int rm = item - r * 528;
        const int j  = rm >> 3, cb = rm & 7;
        const int gr = h0_c - 1 + r, gc = w0_c - 1 + j;
        const bool ok = (item < 2640) && ((unsigned)gr < (unsigned)HH) &&
                        ((unsigned)gc < (unsigned)WWD);
        sv[k] = ok ? *(const bf16x8*)
            &xt[((size_t)(n_c * HH + gr) * WWD + gc) * 64 + cb * 8] : z;
    }
#pragma unroll
    for (int k = 0; k < 4; ++k) {
        const int item = k * 768 + tid;
        if (item < 2640) {
            const int r  = item / 528;
            const int rm = item - r * 528;
            const int j  = rm >> 3, cb = rm & 7;
            *(bf16x8*)&smem[(r * 66 + j) * 64 + ((cb ^ (j & 7)) << 3)] = sv[k];
        }
    }
    __syncthreads();

    for (int t = 0; t < 3; ++t) {
        int n_n = n_c, h0_n = h0_c, w0_n = w0_c;
        if (t < 2) {
            // decode tile t+1 and ISSUE its loads (hide under MFMA + stores)
            const int tau = 96 * xcd + 3 * ii + t + 1;
            n_n = tau / 192;
            const int rem = tau % 192;
            w0_n = (rem / 64) * 64;
            h0_n = (rem % 64) * 3;
#pragma unroll
            for (int k = 0; k < 4; ++k) {
                const int item = k * 768 + tid;
                const int r  = item / 528;
                const int rm = item - r * 528;
                const int j  = rm >> 3, cb = rm & 7;
                const int gr = h0_n - 1 + r, gc = w0_n - 1 + j;
                const bool ok = (item < 2640) && ((unsigned)gr < (unsigned)HH) &&
                                ((unsigned)gc < (unsigned)WWD);
                sv[k] = ok ? *(const bf16x8*)
                    &xt[((size_t)(n_n * HH + gr) * WWD + gc) * 64 + cb * 8] : z;
            }
        }

        // ---- MFMA phase on buffer t&1: 30 ds_reads, 54 MFMAs per wave -----
        const short* __restrict__ xb = &smem[(t & 1) * BUFS];
        f32x4 acc[3];
#pragma unroll
        for (int ih = 0; ih < 3; ++ih) acc[ih] = (f32x4){0.f, 0.f, 0.f, 0.f};

#pragma unroll
        for (int b = 0; b < 6; ++b) {
            const int dj = b >> 1, kc2 = b & 1;
            const int col = mt * 16 + l15 + dj;      // 0..65
            const int blk = (kc2 * 4 + quad) ^ (col & 7);
#pragma unroll
            for (int r = 0; r < 5; ++r) {
                bf16x8 a = *(const bf16x8*)&xb[(r * 66 + col) * 64 + (blk << 3)];
#pragma unroll
                for (int di = 0; di < 3; ++di) {
                    const int ih = r - di;
                    if (ih >= 0 && ih < 3)
                        acc[ih] = __builtin_amdgcn_mfma_f32_16x16x32_bf16(
                            a, Bf[(di * 3 + dj) * 2 + kc2], acc[ih], 0, 0, 0);
                }
            }
        }

        // ---- epilogue: D -> obuf (separate LDS region) --------------------
        {
            const int po = wv * 16 + l15;
            const int o  = po % 3;
            const int p  = po / 3;
            const int si = p >> 2, sj = p & 3;
            const int osi = o * 4 + si;
#pragma unroll
            for (int ih = 0; ih < 3; ++ih)
#pragma unroll
                for (int r4 = 0; r4 < 4; ++r4) {
                    const int wl = mt * 16 + quad * 4 + r4;
                    obuf[(ih * 12 + osi) * 260 + wl * 4 + sj] = acc[ih][r4];
                }
        }
        __syncthreads();                   // obuf visible; xlds(t) reads done

        // ---- coalesced out stores: exactly 1 float4 / thread / ih ---------
#pragma unroll
        for (int ih = 0; ih < 3; ++ih) {
            const int osi = tid >> 6;      // 0..11
            const int c4  = tid & 63;
            const int o = osi >> 2, si = osi & 3;
            const int hh = h0_c + ih;
            const size_t base =
                ((size_t)(n_c * OC + o) * (SS * HH) + (size_t)(SS * hh + si))
                    * (SS * WWD) + (size_t)(4 * w0_c) + c4 * 4;
            *(float4*)&out[base] =
                *(const float4*)&obuf[(ih * 12 + osi) * 260 + c4 * 4];
        }

        if (t < 2) {
            // first use of sv -> vmcnt wait lands HERE, after MFMA + stores
#pragma unroll
            for (int k = 0; k < 4; ++k) {
                const int item = k * 768 + tid;
                if (item < 2640) {
                    const int r  = item / 528;
                    const int rm = item - r * 528;
                    const int j  = rm >> 3, cb = rm & 7;
                    *(bf16x8*)&smem[((t + 1) & 1) * BUFS +
                        (r * 66 + j) * 64 + ((cb ^ (j & 7)) << 3)] = sv[k];
                }
            }
            __syncthreads();               // buf(t+1) visible before MFMA(t+1)
            n_c = n_n; h0_c = h0_n; w0_c = w0_n;
        }
    }
}

extern "C" void kernel_launch(void* const* d_in, const int* in_sizes, int n_in,
                              void* d_out, int out_size, void* d_ws, size_t ws_size,
                              hipStream_t stream) {
    const float* x  = (const float*)d_in[0];
    const float* W1 = (const float*)d_in[1];
    const float* b1 = (const float*)d_in[2];
    const float* W2 = (const float*)d_in[3];
    const float* b2 = (const float*)d_in[4];
    float* out = (float*)d_out;
    short* lwb = (short*)d_ws;                  // 27,648 bf16 = 55 KB
    short* xt  = (short*)d_ws + 32768;          // NHWC bf16 x, 18.9 MB

    prep_kernel<<<112 + 4 * HH * 3, 256, 0, stream>>>(x, W1, b1, W2, b2, lwb, xt);
    meta_up_mfma<<<256, 768, 0, stream>>>(xt, lwb, out);
}